// Round 2
// baseline (1456.589 us; speedup 1.0000x reference)
//
#include <hip/hip_runtime.h>

#define N_NODES 200000
#define N_EDGES 6400000
#define HID 128
#define OUTF 16
#define LAYERS 3
#define EPS 1e-5f

#define NRANGES 16
#define RANGE_N 12500                 // nodes per range
#define NBUCKETS 800
#define BUCKET_N 250                  // nodes per bucket
#define BATCH 5000                    // edges per sort batch
#define NBATCH (N_EDGES / BATCH)      // 1280
#define RCAP 405000                   // range segment capacity (mean 400000, sigma ~612)
#define RBLK (RCAP / BATCH)           // 81 P2 blocks per range
#define BCAP 9500                     // bucket segment capacity (mean 8000, sigma ~89)

typedef unsigned int u32;

__device__ __forceinline__ unsigned short f2bf(float f){
  unsigned int u = __float_as_uint(f);
  u += 0x7fffu + ((u >> 16) & 1u);   // RNE
  return (unsigned short)(u >> 16);
}
__device__ __forceinline__ u32 pack2bf(float lo, float hi){
  return (u32)f2bf(lo) | ((u32)f2bf(hi) << 16);
}

// ---------------- cursor init ----------------

__global__ __launch_bounds__(256) void k_initcur(int* __restrict__ range_cursor,
                                                 int* __restrict__ bucket_cursor){
  int t = blockIdx.x * 256 + threadIdx.x;
  if (t < NRANGES) range_cursor[t] = t * RCAP;
  if (t < NBUCKETS) bucket_cursor[t] = t * BCAP;
}

// ---------------- P1: batch-sort edges into 16 dst ranges (full-line flushes) ----------------
// entry = (dst_local_in_range:14 | src:18); range implicit by segment.

__global__ __launch_bounds__(256) void k_p1(const int* __restrict__ src, const int* __restrict__ dst,
                                            int* __restrict__ range_cursor, u32* __restrict__ ebuf1){
  __shared__ u32 stage[BATCH];
  __shared__ int hist[NRANGES], hist2[NRANGES], hbase[NRANGES], gbase[NRANGES];
  const int tid = threadIdx.x;
  const long e0 = (long)blockIdx.x * BATCH;

  if (tid < NRANGES){ hist[tid] = 0; hist2[tid] = 0; }
  __syncthreads();
  for (int i = tid; i < BATCH; i += 256){
    int d = dst[e0 + i];
    atomicAdd(&hist[d / RANGE_N], 1);
  }
  __syncthreads();
  if (tid == 0){ int run = 0; for (int b = 0; b < NRANGES; b++){ hbase[b] = run; run += hist[b]; } }
  __syncthreads();
  if (tid < NRANGES && hist[tid] > 0) gbase[tid] = atomicAdd(&range_cursor[tid], hist[tid]);
  __syncthreads();
  for (int i = tid; i < BATCH; i += 256){
    int d = dst[e0 + i];
    int s = src[e0 + i];
    int r = d / RANGE_N;
    u32 pk = ((u32)(d - r * RANGE_N) << 18) | (u32)s;
    int p = atomicAdd(&hist2[r], 1);
    stage[hbase[r] + p] = pk;
  }
  __syncthreads();
  for (int b = 0; b < NRANGES; b++){
    int len = hist[b];
    int gb = gbase[b], hb = hbase[b];
    for (int i = tid; i < len; i += 256) ebuf1[gb + i] = stage[hb + i];
  }
}

// ---------------- P2: per-range batch-sort into 50 buckets (full-line flushes) ----------------

__global__ __launch_bounds__(256) void k_p2(const u32* __restrict__ ebuf1, const int* __restrict__ range_cursor,
                                            int* __restrict__ bucket_cursor, u32* __restrict__ ebuf2){
  __shared__ u32 stage[BATCH];
  __shared__ int hist[50], hist2[50], hbase[50], gbase[50];
  const int tid = threadIdx.x;
  const int r = blockIdx.x / RBLK;
  const int chunk = blockIdx.x % RBLK;
  const int rlen = range_cursor[r] - r * RCAP;
  const int i0 = chunk * BATCH;
  const int len = min(BATCH, rlen - i0);
  if (len <= 0) return;
  const u32* seg = ebuf1 + (long)r * RCAP + i0;

  if (tid < 50){ hist[tid] = 0; hist2[tid] = 0; }
  __syncthreads();
  for (int i = tid; i < len; i += 256){
    int dl = (int)(seg[i] >> 18);
    atomicAdd(&hist[dl / BUCKET_N], 1);
  }
  __syncthreads();
  if (tid == 0){ int run = 0; for (int b = 0; b < 50; b++){ hbase[b] = run; run += hist[b]; } }
  __syncthreads();
  if (tid < 50 && hist[tid] > 0) gbase[tid] = atomicAdd(&bucket_cursor[r * 50 + tid], hist[tid]);
  __syncthreads();
  for (int i = tid; i < len; i += 256){
    u32 pk = seg[i];
    int b = (int)(pk >> 18) / BUCKET_N;
    int p = atomicAdd(&hist2[b], 1);
    stage[hbase[b] + p] = pk;
  }
  __syncthreads();
  for (int b = 0; b < 50; b++){
    int l = hist[b];
    if (l == 0) continue;
    int gb = gbase[b], hb = hbase[b];
    for (int i = tid; i < l; i += 256) ebuf2[gb + i] = stage[hb + i];
  }
}

// ---------------- scan of 800 bucket lengths -> bucket_base ----------------

__global__ __launch_bounds__(256) void k_scanb(const int* __restrict__ bucket_cursor,
                                               int* __restrict__ bucket_base){
  __shared__ int q[256];
  int tid = threadIdx.x;
  int v[4]; int sum4 = 0;
  if (tid < 200){
    #pragma unroll
    for (int j = 0; j < 4; j++){ int b = 4 * tid + j; v[j] = bucket_cursor[b] - b * BCAP; sum4 += v[j]; }
  }
  q[tid] = sum4; __syncthreads();
  for (int off = 1; off < 256; off <<= 1){
    int t = (tid >= off) ? q[tid - off] : 0;
    __syncthreads();
    q[tid] += t;
    __syncthreads();
  }
  if (tid < 200){
    int run = q[tid] - sum4;
    #pragma unroll
    for (int j = 0; j < 4; j++){ bucket_base[4 * tid + j] = run; run += v[j]; }
  }
}

// ---------------- P3: per-bucket LDS scatter; writes csr AND row_start ----------------

__global__ __launch_bounds__(256) void k_p3(const u32* __restrict__ ebuf2, const int* __restrict__ bucket_cursor,
                                            const int* __restrict__ bucket_base,
                                            int* __restrict__ csr, int* __restrict__ row_start){
  __shared__ int stage[BCAP];
  __shared__ int hist[BUCKET_N], sbase[BUCKET_N], cur[BUCKET_N];
  __shared__ int q[256];
  const int tid = threadIdx.x;
  const int b = blockIdx.x;
  const int n0 = b * BUCKET_N;
  const int dl0 = (b % 50) * BUCKET_N;
  const int len = min(bucket_cursor[b] - b * BCAP, BCAP);
  const int base = bucket_base[b];
  const u32* seg = ebuf2 + (long)b * BCAP;

  if (tid < BUCKET_N){ hist[tid] = 0; cur[tid] = 0; }
  __syncthreads();
  for (int i = tid; i < len; i += 256){
    int local = (int)(seg[i] >> 18) - dl0;
    local = min(max(local, 0), BUCKET_N - 1);   // safety clamp (statistically unreachable)
    atomicAdd(&hist[local], 1);
  }
  __syncthreads();
  {
    int v = (tid < BUCKET_N) ? hist[tid] : 0;
    q[tid] = v; __syncthreads();
    for (int off = 1; off < 256; off <<= 1){
      int t = (tid >= off) ? q[tid - off] : 0;
      __syncthreads();
      q[tid] += t;
      __syncthreads();
    }
    if (tid < BUCKET_N) sbase[tid] = q[tid] - v;
  }
  __syncthreads();
  for (int i = tid; i < len; i += 256){
    u32 pk = seg[i];
    int local = (int)(pk >> 18) - dl0;
    local = min(max(local, 0), BUCKET_N - 1);
    int pos = atomicAdd(&cur[local], 1);
    stage[sbase[local] + pos] = (int)(pk & 0x3FFFFu);
  }
  __syncthreads();
  for (int i = tid; i < len; i += 256) csr[base + i] = stage[i];
  if (tid < BUCKET_N) row_start[n0 + tid] = base + sbase[tid];
  if (b == NBUCKETS - 1 && tid == 0) row_start[N_NODES] = base + len;
}

// ---------------- GEMM [rows,128] @ [128,128] + optional (relu -> LN) ----------------

__global__ __launch_bounds__(256) void k_gemm128(const float* __restrict__ A,
    const float* __restrict__ W, const float* __restrict__ bias,
    const float* __restrict__ gamma, const float* __restrict__ beta,
    float* __restrict__ xout, u32* __restrict__ xbout, int relu_ln)
{
  __shared__ float As[64][132];
  __shared__ float part[64][4][2];
  __shared__ float mu_s[64], rs_s[64];
  __shared__ float gam_s[128], bet_s[128];
  const int tid = threadIdx.x;
  const long row0 = (long)blockIdx.x * 64;

  const float4* A4 = (const float4*)(A + row0 * HID);
  for (int i = tid; i < 64 * 32; i += 256){
    int r = i >> 5, c = i & 31;
    *(float4*)&As[r][c * 4] = A4[r * 32 + c];
  }
  if (relu_ln && tid < 128){ gam_s[tid] = gamma[tid]; bet_s[tid] = beta[tid]; }
  __syncthreads();

  const int cg = tid & 31;
  const int rg = tid >> 5;
  const int c0 = cg * 4;
  float acc[8][4];
  {
    float4 b = *(const float4*)&bias[c0];
    #pragma unroll
    for (int r = 0; r < 8; r++){ acc[r][0]=b.x; acc[r][1]=b.y; acc[r][2]=b.z; acc[r][3]=b.w; }
  }

  for (int k = 0; k < HID; k += 4){
    float4 w0 = *(const float4*)&W[(k + 0) * HID + c0];
    float4 w1 = *(const float4*)&W[(k + 1) * HID + c0];
    float4 w2 = *(const float4*)&W[(k + 2) * HID + c0];
    float4 w3 = *(const float4*)&W[(k + 3) * HID + c0];
    #pragma unroll
    for (int r = 0; r < 8; r++){
      float4 a = *(const float4*)&As[rg * 8 + r][k];
      acc[r][0] = fmaf(a.w, w3.x, fmaf(a.z, w2.x, fmaf(a.y, w1.x, fmaf(a.x, w0.x, acc[r][0]))));
      acc[r][1] = fmaf(a.w, w3.y, fmaf(a.z, w2.y, fmaf(a.y, w1.y, fmaf(a.x, w0.y, acc[r][1]))));
      acc[r][2] = fmaf(a.w, w3.z, fmaf(a.z, w2.z, fmaf(a.y, w1.z, fmaf(a.x, w0.z, acc[r][2]))));
      acc[r][3] = fmaf(a.w, w3.w, fmaf(a.z, w2.w, fmaf(a.y, w1.w, fmaf(a.x, w0.w, acc[r][3]))));
    }
  }

  if (!relu_ln){
    #pragma unroll
    for (int r = 0; r < 8; r++){
      long row = row0 + rg * 8 + r;
      float4 v; v.x = acc[r][0]; v.y = acc[r][1]; v.z = acc[r][2]; v.w = acc[r][3];
      *(float4*)&xout[row * HID + c0] = v;
      uint2 p; p.x = pack2bf(v.x, v.y); p.y = pack2bf(v.z, v.w);
      *(uint2*)&xbout[(row * HID + c0) >> 1] = p;
    }
  } else {
    __syncthreads();
    #pragma unroll
    for (int r = 0; r < 8; r++){
      float4 v;
      v.x = fmaxf(acc[r][0], 0.f); v.y = fmaxf(acc[r][1], 0.f);
      v.z = fmaxf(acc[r][2], 0.f); v.w = fmaxf(acc[r][3], 0.f);
      *(float4*)&As[rg * 8 + r][c0] = v;
    }
    __syncthreads();
    {
      int row = tid >> 2, qq = tid & 3;
      float s = 0.f, s2 = 0.f;
      #pragma unroll 8
      for (int c = 0; c < 32; c++){ float v = As[row][qq * 32 + c]; s += v; s2 += v * v; }
      part[row][qq][0] = s; part[row][qq][1] = s2;
    }
    __syncthreads();
    if (tid < 64){
      float s  = part[tid][0][0] + part[tid][1][0] + part[tid][2][0] + part[tid][3][0];
      float s2 = part[tid][0][1] + part[tid][1][1] + part[tid][2][1] + part[tid][3][1];
      float mu = s * (1.f / HID);
      float var = s2 * (1.f / HID) - mu * mu;
      mu_s[tid] = mu;
      rs_s[tid] = 1.f / sqrtf(var + EPS);
    }
    __syncthreads();
    for (int i = tid; i < 64 * 32; i += 256){
      int r = i >> 5, c4 = (i & 31) * 4;
      float4 v = *(float4*)&As[r][c4];
      float mu = mu_s[r], rs = rs_s[r];
      v.x = (v.x - mu) * rs * gam_s[c4 + 0] + bet_s[c4 + 0];
      v.y = (v.y - mu) * rs * gam_s[c4 + 1] + bet_s[c4 + 1];
      v.z = (v.z - mu) * rs * gam_s[c4 + 2] + bet_s[c4 + 2];
      v.w = (v.w - mu) * rs * gam_s[c4 + 3] + bet_s[c4 + 3];
      long row = row0 + r;
      *(float4*)&xout[row * HID + c4] = v;
      uint2 p; p.x = pack2bf(v.x, v.y); p.y = pack2bf(v.z, v.w);
      *(uint2*)&xbout[(row * HID + c4) >> 1] = p;
    }
  }
}

// ---------------- edge aggregation ----------------
// One wave per node; dwordx4 gathers: 16 lanes cover one xb row (256B), so each
// vector-mem instruction serves 4 edges (vs 2 with uint2) — half the lane-requests
// for the same bytes. 32 edges per bulk iteration (8 gathers in flight), csr
// prefetch across iterations; unmasked 16-edge mid chunk; masked <=15-edge tail.

__global__ __launch_bounds__(256) void k_agg(const int* __restrict__ row_start, const int* __restrict__ csr,
    const uint4* __restrict__ xb4, const float* __restrict__ x, float* __restrict__ h)
{
  int gid  = blockIdx.x * 256 + threadIdx.x;   // grid: N/4 blocks -> exactly N waves
  int node = gid >> 6;
  int lane = gid & 63;
  int q = lane >> 4;              // 0..3 : edge sub-slot
  int c = lane & 15;              // 16B column chunk (cols 8c..8c+7)
  int s0 = row_start[node], s1 = row_start[node + 1];
  const uint4* xbc = xb4 + c;

  // hoisted self-term (lanes 0..15 own 8 cols each)
  float4 xsa = {0.f,0.f,0.f,0.f}, xsb = {0.f,0.f,0.f,0.f};
  if (q == 0){
    xsa = *(const float4*)&x[(long)node * HID + c * 8];
    xsb = *(const float4*)&x[(long)node * HID + c * 8 + 4];
  }

  float a[8] = {0.f,0.f,0.f,0.f,0.f,0.f,0.f,0.f};

  int base = s0;
  int idx[8];
  if (base + 32 <= s1){
    #pragma unroll
    for (int j = 0; j < 8; j++) idx[j] = csr[base + 4*j + q];
  }
  while (base + 32 <= s1){
    uint4 p[8];
    #pragma unroll
    for (int j = 0; j < 8; j++) p[j] = xbc[(long)idx[j] * 16];
    base += 32;
    if (base + 32 <= s1){
      #pragma unroll
      for (int j = 0; j < 8; j++) idx[j] = csr[base + 4*j + q];
    }
    #pragma unroll
    for (int j = 0; j < 8; j++){
      a[0] += __uint_as_float(p[j].x << 16);
      a[1] += __uint_as_float(p[j].x & 0xffff0000u);
      a[2] += __uint_as_float(p[j].y << 16);
      a[3] += __uint_as_float(p[j].y & 0xffff0000u);
      a[4] += __uint_as_float(p[j].z << 16);
      a[5] += __uint_as_float(p[j].z & 0xffff0000u);
      a[6] += __uint_as_float(p[j].w << 16);
      a[7] += __uint_as_float(p[j].w & 0xffff0000u);
    }
  }
  if (base + 16 <= s1){            // unmasked mid chunk (16 edges)
    int ti[4];
    #pragma unroll
    for (int j = 0; j < 4; j++) ti[j] = csr[base + 4*j + q];
    uint4 p[4];
    #pragma unroll
    for (int j = 0; j < 4; j++) p[j] = xbc[(long)ti[j] * 16];
    #pragma unroll
    for (int j = 0; j < 4; j++){
      a[0] += __uint_as_float(p[j].x << 16);
      a[1] += __uint_as_float(p[j].x & 0xffff0000u);
      a[2] += __uint_as_float(p[j].y << 16);
      a[3] += __uint_as_float(p[j].y & 0xffff0000u);
      a[4] += __uint_as_float(p[j].z << 16);
      a[5] += __uint_as_float(p[j].z & 0xffff0000u);
      a[6] += __uint_as_float(p[j].w << 16);
      a[7] += __uint_as_float(p[j].w & 0xffff0000u);
    }
    base += 16;
  }
  if (base < s1){                  // masked tail (1..15 edges)
    const int s1m1 = s1 - 1;
    const int rem = s1 - base;
    int ti[4];
    #pragma unroll
    for (int j = 0; j < 4; j++) ti[j] = csr[min(base + 4*j + q, s1m1)];
    uint4 p[4];
    #pragma unroll
    for (int j = 0; j < 4; j++) p[j] = xbc[(long)ti[j] * 16];
    #pragma unroll
    for (int j = 0; j < 4; j++){
      bool act = (4*j + q) < rem;
      float f0 = __uint_as_float(p[j].x << 16);
      float f1 = __uint_as_float(p[j].x & 0xffff0000u);
      float f2 = __uint_as_float(p[j].y << 16);
      float f3 = __uint_as_float(p[j].y & 0xffff0000u);
      float f4 = __uint_as_float(p[j].z << 16);
      float f5 = __uint_as_float(p[j].z & 0xffff0000u);
      float f6 = __uint_as_float(p[j].w << 16);
      float f7 = __uint_as_float(p[j].w & 0xffff0000u);
      a[0] += act ? f0 : 0.f;
      a[1] += act ? f1 : 0.f;
      a[2] += act ? f2 : 0.f;
      a[3] += act ? f3 : 0.f;
      a[4] += act ? f4 : 0.f;
      a[5] += act ? f5 : 0.f;
      a[6] += act ? f6 : 0.f;
      a[7] += act ? f7 : 0.f;
    }
  }

  #pragma unroll
  for (int k = 0; k < 8; k++){
    a[k] += __shfl_down(a[k], 32);
    a[k] += __shfl_down(a[k], 16);
  }

  if (q == 0){
    float inv = 1.f / (float)(s1 - s0 + 1);
    long bidx = (long)node * HID + c * 8;
    float4 r0, r1;
    r0.x = (a[0] + xsa.x) * inv;
    r0.y = (a[1] + xsa.y) * inv;
    r0.z = (a[2] + xsa.z) * inv;
    r0.w = (a[3] + xsa.w) * inv;
    r1.x = (a[4] + xsb.x) * inv;
    r1.y = (a[5] + xsb.y) * inv;
    r1.z = (a[6] + xsb.z) * inv;
    r1.w = (a[7] + xsb.w) * inv;
    *(float4*)&h[bidx] = r0;
    *(float4*)&h[bidx + 4] = r1;
  }
}

// ---------------- output GEMM [rows,128] @ [128,16] ----------------

__global__ __launch_bounds__(256) void k_gemm_out(const float* __restrict__ x,
    const float* __restrict__ Wo, const float* __restrict__ bo, float* __restrict__ out)
{
  __shared__ float As[16][132];
  __shared__ float Wl[HID * OUTF];
  const int tid = threadIdx.x;
  const long row0 = (long)blockIdx.x * 16;
  const float4* A4 = (const float4*)(x + row0 * HID);
  for (int i = tid; i < 16 * 32; i += 256){
    int r = i >> 5, c = i & 31;
    *(float4*)&As[r][c * 4] = A4[r * 32 + c];
  }
  for (int i = tid; i < HID * OUTF; i += 256) Wl[i] = Wo[i];
  __syncthreads();
  int col = tid & 15, r = tid >> 4;
  float acc = bo[col];
  for (int k = 0; k < HID; k += 4){
    float4 a = *(const float4*)&As[r][k];
    acc = fmaf(a.x, Wl[(k + 0) * OUTF + col],
          fmaf(a.y, Wl[(k + 1) * OUTF + col],
          fmaf(a.z, Wl[(k + 2) * OUTF + col],
          fmaf(a.w, Wl[(k + 3) * OUTF + col], acc))));
  }
  out[(row0 + r) * OUTF + col] = acc;
}

// ---------------- launch ----------------

extern "C" void kernel_launch(void* const* d_in, const int* in_sizes, int n_in,
                              void* d_out, int out_size, void* d_ws, size_t ws_size,
                              hipStream_t stream)
{
  (void)in_sizes; (void)n_in; (void)out_size; (void)ws_size;
  const float* nodes = (const float*)d_in[0];
  const int*   src   = (const int*)d_in[1];
  const int*   dst   = (const int*)d_in[2];
  const float* W_in  = (const float*)d_in[3];
  const float* b_in  = (const float*)d_in[4];
  const float* Ws    = (const float*)d_in[5];
  const float* bs    = (const float*)d_in[6];
  const float* gam   = (const float*)d_in[7];
  const float* bet   = (const float*)d_in[8];
  const float* W_out = (const float*)d_in[9];
  const float* b_out = (const float*)d_in[10];
  float* out = (float*)d_out;

  size_t off = 0;
  auto bump = [&](size_t bytes) -> char* {
    char* p = (char*)d_ws + off;
    off = (off + bytes + 255) & ~(size_t)255;
    return p;
  };
  int* row_start     = (int*)bump((N_NODES + 1) * sizeof(int));
  int* range_cursor  = (int*)bump(NRANGES * sizeof(int));
  int* bucket_cursor = (int*)bump(NBUCKETS * sizeof(int));
  int* bucket_base   = (int*)bump((NBUCKETS + 1) * sizeof(int));
  int* csr           = (int*)bump((size_t)N_EDGES * sizeof(int));
  float* x           = (float*)bump((size_t)N_NODES * HID * sizeof(float));
  float* h           = (float*)bump((size_t)N_NODES * HID * sizeof(float));
  u32* xb            = (u32*)bump((size_t)N_NODES * HID * sizeof(unsigned short));

  // ebuf1 (16*405000*4 = 25.9MB) aliases x (102MB); ebuf2 (800*9500*4 = 30.4MB) aliases h
  u32* ebuf1 = (u32*)x;
  u32* ebuf2 = (u32*)h;

  k_initcur<<<4, 256, 0, stream>>>(range_cursor, bucket_cursor);
  k_p1<<<NBATCH, 256, 0, stream>>>(src, dst, range_cursor, ebuf1);
  k_p2<<<NRANGES * RBLK, 256, 0, stream>>>(ebuf1, range_cursor, bucket_cursor, ebuf2);
  k_scanb<<<1, 256, 0, stream>>>(bucket_cursor, bucket_base);
  k_p3<<<NBUCKETS, 256, 0, stream>>>(ebuf2, bucket_cursor, bucket_base, csr, row_start);

  k_gemm128<<<N_NODES / 64, 256, 0, stream>>>(nodes, W_in, b_in, nullptr, nullptr, x, xb, 0);
  for (int l = 0; l < LAYERS; l++){
    k_agg<<<N_NODES / 4, 256, 0, stream>>>(row_start, csr, (const uint4*)xb, x, h);
    k_gemm128<<<N_NODES / 64, 256, 0, stream>>>(h, Ws + (size_t)l * HID * HID, bs + l * HID,
                                                gam + l * HID, bet + l * HID, x, xb, 1);
  }
  k_gemm_out<<<N_NODES / 16, 256, 0, stream>>>(x, W_out, b_out, out);
}

// Round 3
// 1400.900 us; speedup vs baseline: 1.0398x; 1.0398x over previous
//
#include <hip/hip_runtime.h>

#define N_NODES 200000
#define N_EDGES 6400000
#define HID 128
#define OUTF 16
#define LAYERS 3
#define EPS 1e-5f

#define NRANGES 16
#define RANGE_N 12500                 // nodes per range
#define NBUCKETS 800
#define BUCKET_N 250                  // nodes per bucket
#define BATCH 5000                    // edges per sort batch
#define NBATCH (N_EDGES / BATCH)      // 1280
#define RCAP 405000                   // range segment capacity (mean 400000, sigma ~612)
#define RBLK (RCAP / BATCH)           // 81 P2 blocks per range
#define BCAP 9500                     // bucket segment capacity (mean 8000, sigma ~89)

typedef unsigned int u32;

__device__ __forceinline__ unsigned short f2bf(float f){
  unsigned int u = __float_as_uint(f);
  u += 0x7fffu + ((u >> 16) & 1u);   // RNE
  return (unsigned short)(u >> 16);
}
__device__ __forceinline__ u32 pack2bf(float lo, float hi){
  return (u32)f2bf(lo) | ((u32)f2bf(hi) << 16);
}

// ---------------- cursor init ----------------

__global__ __launch_bounds__(256) void k_initcur(int* __restrict__ range_cursor,
                                                 int* __restrict__ bucket_cursor){
  int t = blockIdx.x * 256 + threadIdx.x;
  if (t < NRANGES) range_cursor[t] = t * RCAP;
  if (t < NBUCKETS) bucket_cursor[t] = t * BCAP;
}

// ---------------- P1: batch-sort edges into 16 dst ranges (full-line flushes) ----------------
// entry = (dst_local_in_range:14 | src:18); range implicit by segment.

__global__ __launch_bounds__(256) void k_p1(const int* __restrict__ src, const int* __restrict__ dst,
                                            int* __restrict__ range_cursor, u32* __restrict__ ebuf1){
  __shared__ u32 stage[BATCH];
  __shared__ int hist[NRANGES], hist2[NRANGES], hbase[NRANGES], gbase[NRANGES];
  const int tid = threadIdx.x;
  const long e0 = (long)blockIdx.x * BATCH;

  if (tid < NRANGES){ hist[tid] = 0; hist2[tid] = 0; }
  __syncthreads();
  for (int i = tid; i < BATCH; i += 256){
    int d = dst[e0 + i];
    atomicAdd(&hist[d / RANGE_N], 1);
  }
  __syncthreads();
  if (tid == 0){ int run = 0; for (int b = 0; b < NRANGES; b++){ hbase[b] = run; run += hist[b]; } }
  __syncthreads();
  if (tid < NRANGES && hist[tid] > 0) gbase[tid] = atomicAdd(&range_cursor[tid], hist[tid]);
  __syncthreads();
  for (int i = tid; i < BATCH; i += 256){
    int d = dst[e0 + i];
    int s = src[e0 + i];
    int r = d / RANGE_N;
    u32 pk = ((u32)(d - r * RANGE_N) << 18) | (u32)s;
    int p = atomicAdd(&hist2[r], 1);
    stage[hbase[r] + p] = pk;
  }
  __syncthreads();
  for (int b = 0; b < NRANGES; b++){
    int len = hist[b];
    int gb = gbase[b], hb = hbase[b];
    for (int i = tid; i < len; i += 256) ebuf1[gb + i] = stage[hb + i];
  }
}

// ---------------- P2: per-range batch-sort into 50 buckets (full-line flushes) ----------------

__global__ __launch_bounds__(256) void k_p2(const u32* __restrict__ ebuf1, const int* __restrict__ range_cursor,
                                            int* __restrict__ bucket_cursor, u32* __restrict__ ebuf2){
  __shared__ u32 stage[BATCH];
  __shared__ int hist[50], hist2[50], hbase[50], gbase[50];
  const int tid = threadIdx.x;
  const int r = blockIdx.x / RBLK;
  const int chunk = blockIdx.x % RBLK;
  const int rlen = range_cursor[r] - r * RCAP;
  const int i0 = chunk * BATCH;
  const int len = min(BATCH, rlen - i0);
  if (len <= 0) return;
  const u32* seg = ebuf1 + (long)r * RCAP + i0;

  if (tid < 50){ hist[tid] = 0; hist2[tid] = 0; }
  __syncthreads();
  for (int i = tid; i < len; i += 256){
    int dl = (int)(seg[i] >> 18);
    atomicAdd(&hist[dl / BUCKET_N], 1);
  }
  __syncthreads();
  if (tid == 0){ int run = 0; for (int b = 0; b < 50; b++){ hbase[b] = run; run += hist[b]; } }
  __syncthreads();
  if (tid < 50 && hist[tid] > 0) gbase[tid] = atomicAdd(&bucket_cursor[r * 50 + tid], hist[tid]);
  __syncthreads();
  for (int i = tid; i < len; i += 256){
    u32 pk = seg[i];
    int b = (int)(pk >> 18) / BUCKET_N;
    int p = atomicAdd(&hist2[b], 1);
    stage[hbase[b] + p] = pk;
  }
  __syncthreads();
  for (int b = 0; b < 50; b++){
    int l = hist[b];
    if (l == 0) continue;
    int gb = gbase[b], hb = hbase[b];
    for (int i = tid; i < l; i += 256) ebuf2[gb + i] = stage[hb + i];
  }
}

// ---------------- scan of 800 bucket lengths -> bucket_base ----------------

__global__ __launch_bounds__(256) void k_scanb(const int* __restrict__ bucket_cursor,
                                               int* __restrict__ bucket_base){
  __shared__ int q[256];
  int tid = threadIdx.x;
  int v[4]; int sum4 = 0;
  if (tid < 200){
    #pragma unroll
    for (int j = 0; j < 4; j++){ int b = 4 * tid + j; v[j] = bucket_cursor[b] - b * BCAP; sum4 += v[j]; }
  }
  q[tid] = sum4; __syncthreads();
  for (int off = 1; off < 256; off <<= 1){
    int t = (tid >= off) ? q[tid - off] : 0;
    __syncthreads();
    q[tid] += t;
    __syncthreads();
  }
  if (tid < 200){
    int run = q[tid] - sum4;
    #pragma unroll
    for (int j = 0; j < 4; j++){ bucket_base[4 * tid + j] = run; run += v[j]; }
  }
}

// ---------------- P3: per-bucket LDS scatter; writes csr AND row_start ----------------

__global__ __launch_bounds__(256) void k_p3(const u32* __restrict__ ebuf2, const int* __restrict__ bucket_cursor,
                                            const int* __restrict__ bucket_base,
                                            int* __restrict__ csr, int* __restrict__ row_start){
  __shared__ int stage[BCAP];
  __shared__ int hist[BUCKET_N], sbase[BUCKET_N], cur[BUCKET_N];
  __shared__ int q[256];
  const int tid = threadIdx.x;
  const int b = blockIdx.x;
  const int n0 = b * BUCKET_N;
  const int dl0 = (b % 50) * BUCKET_N;
  const int len = min(bucket_cursor[b] - b * BCAP, BCAP);
  const int base = bucket_base[b];
  const u32* seg = ebuf2 + (long)b * BCAP;

  if (tid < BUCKET_N){ hist[tid] = 0; cur[tid] = 0; }
  __syncthreads();
  for (int i = tid; i < len; i += 256){
    int local = (int)(seg[i] >> 18) - dl0;
    local = min(max(local, 0), BUCKET_N - 1);   // safety clamp (statistically unreachable)
    atomicAdd(&hist[local], 1);
  }
  __syncthreads();
  {
    int v = (tid < BUCKET_N) ? hist[tid] : 0;
    q[tid] = v; __syncthreads();
    for (int off = 1; off < 256; off <<= 1){
      int t = (tid >= off) ? q[tid - off] : 0;
      __syncthreads();
      q[tid] += t;
      __syncthreads();
    }
    if (tid < BUCKET_N) sbase[tid] = q[tid] - v;
  }
  __syncthreads();
  for (int i = tid; i < len; i += 256){
    u32 pk = seg[i];
    int local = (int)(pk >> 18) - dl0;
    local = min(max(local, 0), BUCKET_N - 1);
    int pos = atomicAdd(&cur[local], 1);
    stage[sbase[local] + pos] = (int)(pk & 0x3FFFFu);
  }
  __syncthreads();
  for (int i = tid; i < len; i += 256) csr[base + i] = stage[i];
  if (tid < BUCKET_N) row_start[n0 + tid] = base + sbase[tid];
  if (b == NBUCKETS - 1 && tid == 0) row_start[N_NODES] = base + len;
}

// ---------------- GEMM [rows,128] @ [128,128] (first layer, no relu/LN) ----------------

__global__ __launch_bounds__(256) void k_gemm128(const float* __restrict__ A,
    const float* __restrict__ W, const float* __restrict__ bias,
    float* __restrict__ xout, u32* __restrict__ xbout)
{
  __shared__ float As[64][132];
  const int tid = threadIdx.x;
  const long row0 = (long)blockIdx.x * 64;

  const float4* A4 = (const float4*)(A + row0 * HID);
  for (int i = tid; i < 64 * 32; i += 256){
    int r = i >> 5, c = i & 31;
    *(float4*)&As[r][c * 4] = A4[r * 32 + c];
  }
  __syncthreads();

  const int cg = tid & 31;
  const int rg = tid >> 5;
  const int c0 = cg * 4;
  float acc[8][4];
  {
    float4 b = *(const float4*)&bias[c0];
    #pragma unroll
    for (int r = 0; r < 8; r++){ acc[r][0]=b.x; acc[r][1]=b.y; acc[r][2]=b.z; acc[r][3]=b.w; }
  }

  for (int k = 0; k < HID; k += 4){
    float4 w0 = *(const float4*)&W[(k + 0) * HID + c0];
    float4 w1 = *(const float4*)&W[(k + 1) * HID + c0];
    float4 w2 = *(const float4*)&W[(k + 2) * HID + c0];
    float4 w3 = *(const float4*)&W[(k + 3) * HID + c0];
    #pragma unroll
    for (int r = 0; r < 8; r++){
      float4 a = *(const float4*)&As[rg * 8 + r][k];
      acc[r][0] = fmaf(a.w, w3.x, fmaf(a.z, w2.x, fmaf(a.y, w1.x, fmaf(a.x, w0.x, acc[r][0]))));
      acc[r][1] = fmaf(a.w, w3.y, fmaf(a.z, w2.y, fmaf(a.y, w1.y, fmaf(a.x, w0.y, acc[r][1]))));
      acc[r][2] = fmaf(a.w, w3.z, fmaf(a.z, w2.z, fmaf(a.y, w1.z, fmaf(a.x, w0.z, acc[r][2]))));
      acc[r][3] = fmaf(a.w, w3.w, fmaf(a.z, w2.w, fmaf(a.y, w1.w, fmaf(a.x, w0.w, acc[r][3]))));
    }
  }

  #pragma unroll
  for (int r = 0; r < 8; r++){
    long row = row0 + rg * 8 + r;
    float4 v; v.x = acc[r][0]; v.y = acc[r][1]; v.z = acc[r][2]; v.w = acc[r][3];
    *(float4*)&xout[row * HID + c0] = v;
    uint2 p; p.x = pack2bf(v.x, v.y); p.y = pack2bf(v.z, v.w);
    *(uint2*)&xbout[(row * HID + c0) >> 1] = p;
  }
}

// ---------------- fused layer: aggregate 64 nodes into LDS, then GEMM+relu+LN ----------------
// Phase A: 4 waves x 16 nodes each; per node the round-1 uint2 gather (16 edges/iter,
// csr prefetch, unmasked bulk + masked tail); aggregated fp32 row written to As.
// Phase B: identical to previous k_gemm128 relu_ln path, reading As.
// Reads {x_old, xb_old}, writes {x_new, xb_new} (ping-pong -> no inter-block race).

__global__ __launch_bounds__(256) void k_fused(const int* __restrict__ row_start,
    const int* __restrict__ csr, const uint2* __restrict__ xb2,
    const float* __restrict__ x_old,
    const float* __restrict__ W, const float* __restrict__ bias,
    const float* __restrict__ gamma, const float* __restrict__ beta,
    float* __restrict__ xout, u32* __restrict__ xbout)
{
  __shared__ float As[64][132];
  __shared__ float part[64][4][2];
  __shared__ float mu_s[64], rs_s[64];
  __shared__ float gam_s[128], bet_s[128];
  const int tid = threadIdx.x;
  const long row0 = (long)blockIdx.x * 64;

  if (tid < 128){ gam_s[tid] = gamma[tid]; bet_s[tid] = beta[tid]; }

  // ---- Phase A: aggregation into As ----
  {
    const int wv = tid >> 6;
    const int lane = tid & 63;
    const int half = lane >> 5, col = lane & 31;
    const uint2* xbc = xb2 + col;

    for (int i = 0; i < 16; i++){
      const int r = wv * 16 + i;
      const int node = (int)row0 + r;
      const int s0 = row_start[node], s1 = row_start[node + 1];

      float4 xs = {0.f, 0.f, 0.f, 0.f};
      if (half == 0) xs = *(const float4*)&x_old[(long)node * HID + col * 4];

      float a0 = 0.f, a1 = 0.f, a2 = 0.f, a3 = 0.f;
      int base = s0;
      int idx[8];
      if (base + 16 <= s1){
        #pragma unroll
        for (int j = 0; j < 8; j++) idx[j] = csr[base + 2*j + half];
      }
      while (base + 16 <= s1){
        uint2 p[8];
        #pragma unroll
        for (int j = 0; j < 8; j++) p[j] = xbc[(long)idx[j] * 32];
        base += 16;
        if (base + 16 <= s1){
          #pragma unroll
          for (int j = 0; j < 8; j++) idx[j] = csr[base + 2*j + half];
        }
        #pragma unroll
        for (int j = 0; j < 8; j++){
          a0 += __uint_as_float(p[j].x << 16);
          a1 += __uint_as_float(p[j].x & 0xffff0000u);
          a2 += __uint_as_float(p[j].y << 16);
          a3 += __uint_as_float(p[j].y & 0xffff0000u);
        }
      }
      if (base < s1){
        const int s1m1 = s1 - 1;
        int ti[8];
        #pragma unroll
        for (int j = 0; j < 8; j++) ti[j] = csr[min(base + 2*j + half, s1m1)];
        uint2 p[8];
        #pragma unroll
        for (int j = 0; j < 8; j++) p[j] = xbc[(long)ti[j] * 32];
        #pragma unroll
        for (int j = 0; j < 8; j++){
          bool act = (base + 2*j + half) < s1;
          float v0 = __uint_as_float(p[j].x << 16);
          float v1 = __uint_as_float(p[j].x & 0xffff0000u);
          float v2 = __uint_as_float(p[j].y << 16);
          float v3 = __uint_as_float(p[j].y & 0xffff0000u);
          a0 += act ? v0 : 0.f;
          a1 += act ? v1 : 0.f;
          a2 += act ? v2 : 0.f;
          a3 += act ? v3 : 0.f;
        }
      }

      a0 += __shfl_down(a0, 32);
      a1 += __shfl_down(a1, 32);
      a2 += __shfl_down(a2, 32);
      a3 += __shfl_down(a3, 32);

      if (half == 0){
        float inv = 1.f / (float)(s1 - s0 + 1);
        float4 rv;
        rv.x = (a0 + xs.x) * inv;
        rv.y = (a1 + xs.y) * inv;
        rv.z = (a2 + xs.z) * inv;
        rv.w = (a3 + xs.w) * inv;
        *(float4*)&As[r][col * 4] = rv;
      }
    }
  }
  __syncthreads();

  // ---- Phase B: GEMM + relu + LN (identical math to previous k_gemm128 relu_ln=1) ----
  const int cg = tid & 31;
  const int rg = tid >> 5;
  const int c0 = cg * 4;
  float acc[8][4];
  {
    float4 b = *(const float4*)&bias[c0];
    #pragma unroll
    for (int r = 0; r < 8; r++){ acc[r][0]=b.x; acc[r][1]=b.y; acc[r][2]=b.z; acc[r][3]=b.w; }
  }

  for (int k = 0; k < HID; k += 4){
    float4 w0 = *(const float4*)&W[(k + 0) * HID + c0];
    float4 w1 = *(const float4*)&W[(k + 1) * HID + c0];
    float4 w2 = *(const float4*)&W[(k + 2) * HID + c0];
    float4 w3 = *(const float4*)&W[(k + 3) * HID + c0];
    #pragma unroll
    for (int r = 0; r < 8; r++){
      float4 a = *(const float4*)&As[rg * 8 + r][k];
      acc[r][0] = fmaf(a.w, w3.x, fmaf(a.z, w2.x, fmaf(a.y, w1.x, fmaf(a.x, w0.x, acc[r][0]))));
      acc[r][1] = fmaf(a.w, w3.y, fmaf(a.z, w2.y, fmaf(a.y, w1.y, fmaf(a.x, w0.y, acc[r][1]))));
      acc[r][2] = fmaf(a.w, w3.z, fmaf(a.z, w2.z, fmaf(a.y, w1.z, fmaf(a.x, w0.z, acc[r][2]))));
      acc[r][3] = fmaf(a.w, w3.w, fmaf(a.z, w2.w, fmaf(a.y, w1.w, fmaf(a.x, w0.w, acc[r][3]))));
    }
  }

  __syncthreads();
  #pragma unroll
  for (int r = 0; r < 8; r++){
    float4 v;
    v.x = fmaxf(acc[r][0], 0.f); v.y = fmaxf(acc[r][1], 0.f);
    v.z = fmaxf(acc[r][2], 0.f); v.w = fmaxf(acc[r][3], 0.f);
    *(float4*)&As[rg * 8 + r][c0] = v;
  }
  __syncthreads();
  {
    int row = tid >> 2, qq = tid & 3;
    float s = 0.f, s2 = 0.f;
    #pragma unroll 8
    for (int c = 0; c < 32; c++){ float v = As[row][qq * 32 + c]; s += v; s2 += v * v; }
    part[row][qq][0] = s; part[row][qq][1] = s2;
  }
  __syncthreads();
  if (tid < 64){
    float s  = part[tid][0][0] + part[tid][1][0] + part[tid][2][0] + part[tid][3][0];
    float s2 = part[tid][0][1] + part[tid][1][1] + part[tid][2][1] + part[tid][3][1];
    float mu = s * (1.f / HID);
    float var = s2 * (1.f / HID) - mu * mu;
    mu_s[tid] = mu;
    rs_s[tid] = 1.f / sqrtf(var + EPS);
  }
  __syncthreads();
  for (int i = tid; i < 64 * 32; i += 256){
    int r = i >> 5, c4 = (i & 31) * 4;
    float4 v = *(float4*)&As[r][c4];
    float mu = mu_s[r], rs = rs_s[r];
    v.x = (v.x - mu) * rs * gam_s[c4 + 0] + bet_s[c4 + 0];
    v.y = (v.y - mu) * rs * gam_s[c4 + 1] + bet_s[c4 + 1];
    v.z = (v.z - mu) * rs * gam_s[c4 + 2] + bet_s[c4 + 2];
    v.w = (v.w - mu) * rs * gam_s[c4 + 3] + bet_s[c4 + 3];
    long row = row0 + r;
    *(float4*)&xout[row * HID + c4] = v;
    uint2 p; p.x = pack2bf(v.x, v.y); p.y = pack2bf(v.z, v.w);
    *(uint2*)&xbout[(row * HID + c4) >> 1] = p;
  }
}

// ---------------- output GEMM [rows,128] @ [128,16] ----------------

__global__ __launch_bounds__(256) void k_gemm_out(const float* __restrict__ x,
    const float* __restrict__ Wo, const float* __restrict__ bo, float* __restrict__ out)
{
  __shared__ float As[16][132];
  __shared__ float Wl[HID * OUTF];
  const int tid = threadIdx.x;
  const long row0 = (long)blockIdx.x * 16;
  const float4* A4 = (const float4*)(x + row0 * HID);
  for (int i = tid; i < 16 * 32; i += 256){
    int r = i >> 5, c = i & 31;
    *(float4*)&As[r][c * 4] = A4[r * 32 + c];
  }
  for (int i = tid; i < HID * OUTF; i += 256) Wl[i] = Wo[i];
  __syncthreads();
  int col = tid & 15, r = tid >> 4;
  float acc = bo[col];
  for (int k = 0; k < HID; k += 4){
    float4 a = *(const float4*)&As[r][k];
    acc = fmaf(a.x, Wl[(k + 0) * OUTF + col],
          fmaf(a.y, Wl[(k + 1) * OUTF + col],
          fmaf(a.z, Wl[(k + 2) * OUTF + col],
          fmaf(a.w, Wl[(k + 3) * OUTF + col], acc))));
  }
  out[(row0 + r) * OUTF + col] = acc;
}

// ---------------- launch ----------------

extern "C" void kernel_launch(void* const* d_in, const int* in_sizes, int n_in,
                              void* d_out, int out_size, void* d_ws, size_t ws_size,
                              hipStream_t stream)
{
  (void)in_sizes; (void)n_in; (void)out_size; (void)ws_size;
  const float* nodes = (const float*)d_in[0];
  const int*   src   = (const int*)d_in[1];
  const int*   dst   = (const int*)d_in[2];
  const float* W_in  = (const float*)d_in[3];
  const float* b_in  = (const float*)d_in[4];
  const float* Ws    = (const float*)d_in[5];
  const float* bs    = (const float*)d_in[6];
  const float* gam   = (const float*)d_in[7];
  const float* bet   = (const float*)d_in[8];
  const float* W_out = (const float*)d_in[9];
  const float* b_out = (const float*)d_in[10];
  float* out = (float*)d_out;

  size_t off = 0;
  auto bump = [&](size_t bytes) -> char* {
    char* p = (char*)d_ws + off;
    off = (off + bytes + 255) & ~(size_t)255;
    return p;
  };
  int* row_start     = (int*)bump((N_NODES + 1) * sizeof(int));
  int* range_cursor  = (int*)bump(NRANGES * sizeof(int));
  int* bucket_cursor = (int*)bump(NBUCKETS * sizeof(int));
  int* bucket_base   = (int*)bump((NBUCKETS + 1) * sizeof(int));
  int* csr           = (int*)bump((size_t)N_EDGES * sizeof(int));
  float* x0          = (float*)bump((size_t)N_NODES * HID * sizeof(float));
  float* x1          = (float*)bump((size_t)N_NODES * HID * sizeof(float));
  u32* xb0           = (u32*)bump((size_t)N_NODES * HID * sizeof(unsigned short));
  u32* xb1           = (u32*)bump((size_t)N_NODES * HID * sizeof(unsigned short));

  // ebuf1 (25.9MB) aliases x0 (102MB), consumed by P2 before x0 is written;
  // ebuf2 (30.4MB) aliases x1 (102MB), consumed by P3 before x1 is written.
  u32* ebuf1 = (u32*)x0;
  u32* ebuf2 = (u32*)x1;

  k_initcur<<<4, 256, 0, stream>>>(range_cursor, bucket_cursor);
  k_p1<<<NBATCH, 256, 0, stream>>>(src, dst, range_cursor, ebuf1);
  k_p2<<<NRANGES * RBLK, 256, 0, stream>>>(ebuf1, range_cursor, bucket_cursor, ebuf2);
  k_scanb<<<1, 256, 0, stream>>>(bucket_cursor, bucket_base);
  k_p3<<<NBUCKETS, 256, 0, stream>>>(ebuf2, bucket_cursor, bucket_base, csr, row_start);

  k_gemm128<<<N_NODES / 64, 256, 0, stream>>>(nodes, W_in, b_in, x0, xb0);

  const float* xi = x0;  float* xo = x1;
  const u32*   xbi = xb0; u32*  xbo = xb1;
  for (int l = 0; l < LAYERS; l++){
    k_fused<<<N_NODES / 64, 256, 0, stream>>>(row_start, csr, (const uint2*)xbi, xi,
                                              Ws + (size_t)l * HID * HID, bs + l * HID,
                                              gam + l * HID, bet + l * HID, xo, xbo);
    const float* tx = xi; xi = xo; xo = (float*)tx;
    const u32* tb = xbi; xbi = xbo; xbo = (u32*)tb;
  }

  k_gemm_out<<<N_NODES / 16, 256, 0, stream>>>(xi, W_out, b_out, out);
}

// Round 4
// 1357.673 us; speedup vs baseline: 1.0729x; 1.0318x over previous
//
#include <hip/hip_runtime.h>

#define N_NODES 200000
#define N_EDGES 6400000
#define HID 128
#define OUTF 16
#define LAYERS 3
#define EPS 1e-5f

#define NRANGES 16
#define RANGE_N 12500                 // nodes per range
#define NBUCKETS 800
#define BUCKET_N 250                  // nodes per bucket
#define BATCH 5000                    // edges per sort batch
#define NBATCH (N_EDGES / BATCH)      // 1280
#define RCAP 405000                   // range segment capacity (mean 400000, sigma ~612)
#define RBLK (RCAP / BATCH)           // 81 P2 blocks per range
#define BCAP 9500                     // bucket segment capacity (mean 8000, sigma ~89)

#define FTILE 32                      // fused-layer tile rows (LDS 16.9KB -> 8 blocks/CU)

typedef unsigned int u32;

__device__ __forceinline__ unsigned short f2bf(float f){
  unsigned int u = __float_as_uint(f);
  u += 0x7fffu + ((u >> 16) & 1u);   // RNE
  return (unsigned short)(u >> 16);
}
__device__ __forceinline__ u32 pack2bf(float lo, float hi){
  return (u32)f2bf(lo) | ((u32)f2bf(hi) << 16);
}

// ---------------- cursor init ----------------

__global__ __launch_bounds__(256) void k_initcur(int* __restrict__ range_cursor,
                                                 int* __restrict__ bucket_cursor){
  int t = blockIdx.x * 256 + threadIdx.x;
  if (t < NRANGES) range_cursor[t] = t * RCAP;
  if (t < NBUCKETS) bucket_cursor[t] = t * BCAP;
}

// ---------------- P1: batch-sort edges into 16 dst ranges (full-line flushes) ----------------
// entry = (dst_local_in_range:14 | src:18); range implicit by segment.

__global__ __launch_bounds__(256) void k_p1(const int* __restrict__ src, const int* __restrict__ dst,
                                            int* __restrict__ range_cursor, u32* __restrict__ ebuf1){
  __shared__ u32 stage[BATCH];
  __shared__ int hist[NRANGES], hist2[NRANGES], hbase[NRANGES], gbase[NRANGES];
  const int tid = threadIdx.x;
  const long e0 = (long)blockIdx.x * BATCH;

  if (tid < NRANGES){ hist[tid] = 0; hist2[tid] = 0; }
  __syncthreads();
  for (int i = tid; i < BATCH; i += 256){
    int d = dst[e0 + i];
    atomicAdd(&hist[d / RANGE_N], 1);
  }
  __syncthreads();
  if (tid == 0){ int run = 0; for (int b = 0; b < NRANGES; b++){ hbase[b] = run; run += hist[b]; } }
  __syncthreads();
  if (tid < NRANGES && hist[tid] > 0) gbase[tid] = atomicAdd(&range_cursor[tid], hist[tid]);
  __syncthreads();
  for (int i = tid; i < BATCH; i += 256){
    int d = dst[e0 + i];
    int s = src[e0 + i];
    int r = d / RANGE_N;
    u32 pk = ((u32)(d - r * RANGE_N) << 18) | (u32)s;
    int p = atomicAdd(&hist2[r], 1);
    stage[hbase[r] + p] = pk;
  }
  __syncthreads();
  for (int b = 0; b < NRANGES; b++){
    int len = hist[b];
    int gb = gbase[b], hb = hbase[b];
    for (int i = tid; i < len; i += 256) ebuf1[gb + i] = stage[hb + i];
  }
}

// ---------------- P2: per-range batch-sort into 50 buckets (full-line flushes) ----------------

__global__ __launch_bounds__(256) void k_p2(const u32* __restrict__ ebuf1, const int* __restrict__ range_cursor,
                                            int* __restrict__ bucket_cursor, u32* __restrict__ ebuf2){
  __shared__ u32 stage[BATCH];
  __shared__ int hist[50], hist2[50], hbase[50], gbase[50];
  const int tid = threadIdx.x;
  const int r = blockIdx.x / RBLK;
  const int chunk = blockIdx.x % RBLK;
  const int rlen = range_cursor[r] - r * RCAP;
  const int i0 = chunk * BATCH;
  const int len = min(BATCH, rlen - i0);
  if (len <= 0) return;
  const u32* seg = ebuf1 + (long)r * RCAP + i0;

  if (tid < 50){ hist[tid] = 0; hist2[tid] = 0; }
  __syncthreads();
  for (int i = tid; i < len; i += 256){
    int dl = (int)(seg[i] >> 18);
    atomicAdd(&hist[dl / BUCKET_N], 1);
  }
  __syncthreads();
  if (tid == 0){ int run = 0; for (int b = 0; b < 50; b++){ hbase[b] = run; run += hist[b]; } }
  __syncthreads();
  if (tid < 50 && hist[tid] > 0) gbase[tid] = atomicAdd(&bucket_cursor[r * 50 + tid], hist[tid]);
  __syncthreads();
  for (int i = tid; i < len; i += 256){
    u32 pk = seg[i];
    int b = (int)(pk >> 18) / BUCKET_N;
    int p = atomicAdd(&hist2[b], 1);
    stage[hbase[b] + p] = pk;
  }
  __syncthreads();
  for (int b = 0; b < 50; b++){
    int l = hist[b];
    if (l == 0) continue;
    int gb = gbase[b], hb = hbase[b];
    for (int i = tid; i < l; i += 256) ebuf2[gb + i] = stage[hb + i];
  }
}

// ---------------- scan of 800 bucket lengths -> bucket_base ----------------

__global__ __launch_bounds__(256) void k_scanb(const int* __restrict__ bucket_cursor,
                                               int* __restrict__ bucket_base){
  __shared__ int q[256];
  int tid = threadIdx.x;
  int v[4]; int sum4 = 0;
  if (tid < 200){
    #pragma unroll
    for (int j = 0; j < 4; j++){ int b = 4 * tid + j; v[j] = bucket_cursor[b] - b * BCAP; sum4 += v[j]; }
  }
  q[tid] = sum4; __syncthreads();
  for (int off = 1; off < 256; off <<= 1){
    int t = (tid >= off) ? q[tid - off] : 0;
    __syncthreads();
    q[tid] += t;
    __syncthreads();
  }
  if (tid < 200){
    int run = q[tid] - sum4;
    #pragma unroll
    for (int j = 0; j < 4; j++){ bucket_base[4 * tid + j] = run; run += v[j]; }
  }
}

// ---------------- P3: per-bucket LDS scatter; writes csr AND row_start ----------------

__global__ __launch_bounds__(256) void k_p3(const u32* __restrict__ ebuf2, const int* __restrict__ bucket_cursor,
                                            const int* __restrict__ bucket_base,
                                            int* __restrict__ csr, int* __restrict__ row_start){
  __shared__ int stage[BCAP];
  __shared__ int hist[BUCKET_N], sbase[BUCKET_N], cur[BUCKET_N];
  __shared__ int q[256];
  const int tid = threadIdx.x;
  const int b = blockIdx.x;
  const int n0 = b * BUCKET_N;
  const int dl0 = (b % 50) * BUCKET_N;
  const int len = min(bucket_cursor[b] - b * BCAP, BCAP);
  const int base = bucket_base[b];
  const u32* seg = ebuf2 + (long)b * BCAP;

  if (tid < BUCKET_N){ hist[tid] = 0; cur[tid] = 0; }
  __syncthreads();
  for (int i = tid; i < len; i += 256){
    int local = (int)(seg[i] >> 18) - dl0;
    local = min(max(local, 0), BUCKET_N - 1);   // safety clamp (statistically unreachable)
    atomicAdd(&hist[local], 1);
  }
  __syncthreads();
  {
    int v = (tid < BUCKET_N) ? hist[tid] : 0;
    q[tid] = v; __syncthreads();
    for (int off = 1; off < 256; off <<= 1){
      int t = (tid >= off) ? q[tid - off] : 0;
      __syncthreads();
      q[tid] += t;
      __syncthreads();
    }
    if (tid < BUCKET_N) sbase[tid] = q[tid] - v;
  }
  __syncthreads();
  for (int i = tid; i < len; i += 256){
    u32 pk = seg[i];
    int local = (int)(pk >> 18) - dl0;
    local = min(max(local, 0), BUCKET_N - 1);
    int pos = atomicAdd(&cur[local], 1);
    stage[sbase[local] + pos] = (int)(pk & 0x3FFFFu);
  }
  __syncthreads();
  for (int i = tid; i < len; i += 256) csr[base + i] = stage[i];
  if (tid < BUCKET_N) row_start[n0 + tid] = base + sbase[tid];
  if (b == NBUCKETS - 1 && tid == 0) row_start[N_NODES] = base + len;
}

// ---------------- GEMM [rows,128] @ [128,128] (first layer, no relu/LN) ----------------

__global__ __launch_bounds__(256) void k_gemm128(const float* __restrict__ A,
    const float* __restrict__ W, const float* __restrict__ bias,
    float* __restrict__ xout, u32* __restrict__ xbout)
{
  __shared__ float As[64][132];
  const int tid = threadIdx.x;
  const long row0 = (long)blockIdx.x * 64;

  const float4* A4 = (const float4*)(A + row0 * HID);
  for (int i = tid; i < 64 * 32; i += 256){
    int r = i >> 5, c = i & 31;
    *(float4*)&As[r][c * 4] = A4[r * 32 + c];
  }
  __syncthreads();

  const int cg = tid & 31;
  const int rg = tid >> 5;
  const int c0 = cg * 4;
  float acc[8][4];
  {
    float4 b = *(const float4*)&bias[c0];
    #pragma unroll
    for (int r = 0; r < 8; r++){ acc[r][0]=b.x; acc[r][1]=b.y; acc[r][2]=b.z; acc[r][3]=b.w; }
  }

  for (int k = 0; k < HID; k += 4){
    float4 w0 = *(const float4*)&W[(k + 0) * HID + c0];
    float4 w1 = *(const float4*)&W[(k + 1) * HID + c0];
    float4 w2 = *(const float4*)&W[(k + 2) * HID + c0];
    float4 w3 = *(const float4*)&W[(k + 3) * HID + c0];
    #pragma unroll
    for (int r = 0; r < 8; r++){
      float4 a = *(const float4*)&As[rg * 8 + r][k];
      acc[r][0] = fmaf(a.w, w3.x, fmaf(a.z, w2.x, fmaf(a.y, w1.x, fmaf(a.x, w0.x, acc[r][0]))));
      acc[r][1] = fmaf(a.w, w3.y, fmaf(a.z, w2.y, fmaf(a.y, w1.y, fmaf(a.x, w0.y, acc[r][1]))));
      acc[r][2] = fmaf(a.w, w3.z, fmaf(a.z, w2.z, fmaf(a.y, w1.z, fmaf(a.x, w0.z, acc[r][2]))));
      acc[r][3] = fmaf(a.w, w3.w, fmaf(a.z, w2.w, fmaf(a.y, w1.w, fmaf(a.x, w0.w, acc[r][3]))));
    }
  }

  #pragma unroll
  for (int r = 0; r < 8; r++){
    long row = row0 + rg * 8 + r;
    float4 v; v.x = acc[r][0]; v.y = acc[r][1]; v.z = acc[r][2]; v.w = acc[r][3];
    *(float4*)&xout[row * HID + c0] = v;
    uint2 p; p.x = pack2bf(v.x, v.y); p.y = pack2bf(v.z, v.w);
    *(uint2*)&xbout[(row * HID + c0) >> 1] = p;
  }
}

// ---------------- fused layer: aggregate 32 nodes into LDS, then GEMM+relu+LN ----------------
// Phase A: 4 waves x 8 nodes each; per node the uint2 gather (16 edges/iter,
// csr prefetch, unmasked bulk + masked tail); aggregated fp32 row -> As.
// Phase B: acc[4][4] per thread; relu; LN stats via 32-lane half-wave shfl_xor
// butterfly (no LDS); normalize in-register; store x + bf16-packed xb directly.
// LDS = As only (16.9 KB) -> 8 blocks/CU -> 32 waves/CU for the gather phase.

__global__ __launch_bounds__(256) void k_fused(const int* __restrict__ row_start,
    const int* __restrict__ csr, const uint2* __restrict__ xb2,
    const float* __restrict__ x_old,
    const float* __restrict__ W, const float* __restrict__ bias,
    const float* __restrict__ gamma, const float* __restrict__ beta,
    float* __restrict__ xout, u32* __restrict__ xbout)
{
  __shared__ float As[FTILE][132];
  const int tid = threadIdx.x;
  const long row0 = (long)blockIdx.x * FTILE;

  // ---- Phase A: aggregation into As ----
  {
    const int wv = tid >> 6;
    const int lane = tid & 63;
    const int half = lane >> 5, col = lane & 31;
    const uint2* xbc = xb2 + col;

    for (int i = 0; i < FTILE / 4; i++){
      const int r = wv * (FTILE / 4) + i;
      const int node = (int)row0 + r;
      const int s0 = row_start[node], s1 = row_start[node + 1];

      float4 xs = {0.f, 0.f, 0.f, 0.f};
      if (half == 0) xs = *(const float4*)&x_old[(long)node * HID + col * 4];

      float a0 = 0.f, a1 = 0.f, a2 = 0.f, a3 = 0.f;
      int base = s0;
      int idx[8];
      if (base + 16 <= s1){
        #pragma unroll
        for (int j = 0; j < 8; j++) idx[j] = csr[base + 2*j + half];
      }
      while (base + 16 <= s1){
        uint2 p[8];
        #pragma unroll
        for (int j = 0; j < 8; j++) p[j] = xbc[(long)idx[j] * 32];
        base += 16;
        if (base + 16 <= s1){
          #pragma unroll
          for (int j = 0; j < 8; j++) idx[j] = csr[base + 2*j + half];
        }
        #pragma unroll
        for (int j = 0; j < 8; j++){
          a0 += __uint_as_float(p[j].x << 16);
          a1 += __uint_as_float(p[j].x & 0xffff0000u);
          a2 += __uint_as_float(p[j].y << 16);
          a3 += __uint_as_float(p[j].y & 0xffff0000u);
        }
      }
      if (base < s1){
        const int s1m1 = s1 - 1;
        int ti[8];
        #pragma unroll
        for (int j = 0; j < 8; j++) ti[j] = csr[min(base + 2*j + half, s1m1)];
        uint2 p[8];
        #pragma unroll
        for (int j = 0; j < 8; j++) p[j] = xbc[(long)ti[j] * 32];
        #pragma unroll
        for (int j = 0; j < 8; j++){
          bool act = (base + 2*j + half) < s1;
          float v0 = __uint_as_float(p[j].x << 16);
          float v1 = __uint_as_float(p[j].x & 0xffff0000u);
          float v2 = __uint_as_float(p[j].y << 16);
          float v3 = __uint_as_float(p[j].y & 0xffff0000u);
          a0 += act ? v0 : 0.f;
          a1 += act ? v1 : 0.f;
          a2 += act ? v2 : 0.f;
          a3 += act ? v3 : 0.f;
        }
      }

      a0 += __shfl_down(a0, 32);
      a1 += __shfl_down(a1, 32);
      a2 += __shfl_down(a2, 32);
      a3 += __shfl_down(a3, 32);

      if (half == 0){
        float inv = 1.f / (float)(s1 - s0 + 1);
        float4 rv;
        rv.x = (a0 + xs.x) * inv;
        rv.y = (a1 + xs.y) * inv;
        rv.z = (a2 + xs.z) * inv;
        rv.w = (a3 + xs.w) * inv;
        *(float4*)&As[r][col * 4] = rv;
      }
    }
  }
  __syncthreads();

  // ---- Phase B: GEMM + relu + LN (in-register; half-wave butterfly stats) ----
  const int cg = tid & 31;
  const int rg = tid >> 5;             // 0..7 -> 4 rows each
  const int c0 = cg * 4;
  float acc[4][4];
  {
    float4 b = *(const float4*)&bias[c0];
    #pragma unroll
    for (int r = 0; r < 4; r++){ acc[r][0]=b.x; acc[r][1]=b.y; acc[r][2]=b.z; acc[r][3]=b.w; }
  }

  for (int k = 0; k < HID; k += 4){
    float4 w0 = *(const float4*)&W[(k + 0) * HID + c0];
    float4 w1 = *(const float4*)&W[(k + 1) * HID + c0];
    float4 w2 = *(const float4*)&W[(k + 2) * HID + c0];
    float4 w3 = *(const float4*)&W[(k + 3) * HID + c0];
    #pragma unroll
    for (int r = 0; r < 4; r++){
      float4 a = *(const float4*)&As[rg * 4 + r][k];
      acc[r][0] = fmaf(a.w, w3.x, fmaf(a.z, w2.x, fmaf(a.y, w1.x, fmaf(a.x, w0.x, acc[r][0]))));
      acc[r][1] = fmaf(a.w, w3.y, fmaf(a.z, w2.y, fmaf(a.y, w1.y, fmaf(a.x, w0.y, acc[r][1]))));
      acc[r][2] = fmaf(a.w, w3.z, fmaf(a.z, w2.z, fmaf(a.y, w1.z, fmaf(a.x, w0.z, acc[r][2]))));
      acc[r][3] = fmaf(a.w, w3.w, fmaf(a.z, w2.w, fmaf(a.y, w1.w, fmaf(a.x, w0.w, acc[r][3]))));
    }
  }

  // relu + per-row {sum, sumsq} partials over this thread's 4 cols
  float s[4], s2[4];
  #pragma unroll
  for (int r = 0; r < 4; r++){
    float v0 = fmaxf(acc[r][0], 0.f);
    float v1 = fmaxf(acc[r][1], 0.f);
    float v2 = fmaxf(acc[r][2], 0.f);
    float v3 = fmaxf(acc[r][3], 0.f);
    acc[r][0] = v0; acc[r][1] = v1; acc[r][2] = v2; acc[r][3] = v3;
    s[r]  = (v0 + v1) + (v2 + v3);
    s2[r] = fmaf(v0, v0, fmaf(v1, v1, fmaf(v2, v2, v3 * v3)));
  }
  // butterfly across the 32 lanes holding this row group (xor masks stay in half-wave)
  #pragma unroll
  for (int m = 1; m < 32; m <<= 1){
    #pragma unroll
    for (int r = 0; r < 4; r++){
      s[r]  += __shfl_xor(s[r],  m);
      s2[r] += __shfl_xor(s2[r], m);
    }
  }

  const float4 gm = *(const float4*)&gamma[c0];
  const float4 bt = *(const float4*)&beta[c0];
  #pragma unroll
  for (int r = 0; r < 4; r++){
    float mu = s[r] * (1.f / HID);
    float var = s2[r] * (1.f / HID) - mu * mu;
    float rs = 1.f / sqrtf(var + EPS);
    float4 v;
    v.x = (acc[r][0] - mu) * rs * gm.x + bt.x;
    v.y = (acc[r][1] - mu) * rs * gm.y + bt.y;
    v.z = (acc[r][2] - mu) * rs * gm.z + bt.z;
    v.w = (acc[r][3] - mu) * rs * gm.w + bt.w;
    long row = row0 + rg * 4 + r;
    *(float4*)&xout[row * HID + c0] = v;
    uint2 p; p.x = pack2bf(v.x, v.y); p.y = pack2bf(v.z, v.w);
    *(uint2*)&xbout[(row * HID + c0) >> 1] = p;
  }
}

// ---------------- output GEMM [rows,128] @ [128,16] ----------------

__global__ __launch_bounds__(256) void k_gemm_out(const float* __restrict__ x,
    const float* __restrict__ Wo, const float* __restrict__ bo, float* __restrict__ out)
{
  __shared__ float As[16][132];
  __shared__ float Wl[HID * OUTF];
  const int tid = threadIdx.x;
  const long row0 = (long)blockIdx.x * 16;
  const float4* A4 = (const float4*)(x + row0 * HID);
  for (int i = tid; i < 16 * 32; i += 256){
    int r = i >> 5, c = i & 31;
    *(float4*)&As[r][c * 4] = A4[r * 32 + c];
  }
  for (int i = tid; i < HID * OUTF; i += 256) Wl[i] = Wo[i];
  __syncthreads();
  int col = tid & 15, r = tid >> 4;
  float acc = bo[col];
  for (int k = 0; k < HID; k += 4){
    float4 a = *(const float4*)&As[r][k];
    acc = fmaf(a.x, Wl[(k + 0) * OUTF + col],
          fmaf(a.y, Wl[(k + 1) * OUTF + col],
          fmaf(a.z, Wl[(k + 2) * OUTF + col],
          fmaf(a.w, Wl[(k + 3) * OUTF + col], acc))));
  }
  out[(row0 + r) * OUTF + col] = acc;
}

// ---------------- launch ----------------

extern "C" void kernel_launch(void* const* d_in, const int* in_sizes, int n_in,
                              void* d_out, int out_size, void* d_ws, size_t ws_size,
                              hipStream_t stream)
{
  (void)in_sizes; (void)n_in; (void)out_size; (void)ws_size;
  const float* nodes = (const float*)d_in[0];
  const int*   src   = (const int*)d_in[1];
  const int*   dst   = (const int*)d_in[2];
  const float* W_in  = (const float*)d_in[3];
  const float* b_in  = (const float*)d_in[4];
  const float* Ws    = (const float*)d_in[5];
  const float* bs    = (const float*)d_in[6];
  const float* gam   = (const float*)d_in[7];
  const float* bet   = (const float*)d_in[8];
  const float* W_out = (const float*)d_in[9];
  const float* b_out = (const float*)d_in[10];
  float* out = (float*)d_out;

  size_t off = 0;
  auto bump = [&](size_t bytes) -> char* {
    char* p = (char*)d_ws + off;
    off = (off + bytes + 255) & ~(size_t)255;
    return p;
  };
  int* row_start     = (int*)bump((N_NODES + 1) * sizeof(int));
  int* range_cursor  = (int*)bump(NRANGES * sizeof(int));
  int* bucket_cursor = (int*)bump(NBUCKETS * sizeof(int));
  int* bucket_base   = (int*)bump((NBUCKETS + 1) * sizeof(int));
  int* csr           = (int*)bump((size_t)N_EDGES * sizeof(int));
  float* x0          = (float*)bump((size_t)N_NODES * HID * sizeof(float));
  float* x1          = (float*)bump((size_t)N_NODES * HID * sizeof(float));
  u32* xb0           = (u32*)bump((size_t)N_NODES * HID * sizeof(unsigned short));
  u32* xb1           = (u32*)bump((size_t)N_NODES * HID * sizeof(unsigned short));

  // ebuf1 (25.9MB) aliases x0 (102MB), consumed by P2 before x0 is written;
  // ebuf2 (30.4MB) aliases x1 (102MB), consumed by P3 before x1 is written.
  u32* ebuf1 = (u32*)x0;
  u32* ebuf2 = (u32*)x1;

  k_initcur<<<4, 256, 0, stream>>>(range_cursor, bucket_cursor);
  k_p1<<<NBATCH, 256, 0, stream>>>(src, dst, range_cursor, ebuf1);
  k_p2<<<NRANGES * RBLK, 256, 0, stream>>>(ebuf1, range_cursor, bucket_cursor, ebuf2);
  k_scanb<<<1, 256, 0, stream>>>(bucket_cursor, bucket_base);
  k_p3<<<NBUCKETS, 256, 0, stream>>>(ebuf2, bucket_cursor, bucket_base, csr, row_start);

  k_gemm128<<<N_NODES / 64, 256, 0, stream>>>(nodes, W_in, b_in, x0, xb0);

  const float* xi = x0;  float* xo = x1;
  const u32*   xbi = xb0; u32*  xbo = xb1;
  for (int l = 0; l < LAYERS; l++){
    k_fused<<<N_NODES / FTILE, 256, 0, stream>>>(row_start, csr, (const uint2*)xbi, xi,
                                                 Ws + (size_t)l * HID * HID, bs + l * HID,
                                                 gam + l * HID, bet + l * HID, xo, xbo);
    const float* tx = xi; xi = xo; xo = (float*)tx;
    const u32* tb = xbi; xbi = xbo; xbo = (u32*)tb;
  }

  k_gemm_out<<<N_NODES / 16, 256, 0, stream>>>(xi, W_out, b_out, out);
}

// Round 5
// 1218.231 us; speedup vs baseline: 1.1957x; 1.1145x over previous
//
#include <hip/hip_runtime.h>

#define N_NODES 200000
#define N_EDGES 6400000
#define HID 128
#define OUTF 16
#define LAYERS 3
#define EPS 1e-5f

#define NRANGES 16
#define RANGE_N 12500                 // nodes per range
#define NBUCKETS 800
#define BUCKET_N 250                  // nodes per bucket
#define BATCH 5000                    // edges per sort batch
#define NBATCH (N_EDGES / BATCH)      // 1280
#define RCAP 405000                   // range segment capacity (mean 400000, sigma ~612)
#define RBLK (RCAP / BATCH)           // 81 P2 blocks per range
#define BCAP 9500                     // bucket segment capacity (mean 8000, sigma ~89)

#define FTILE 32                      // fused-layer tile rows (LDS 16.9KB -> 8 blocks/CU)

typedef unsigned int u32;

__device__ __forceinline__ unsigned short f2bf(float f){
  unsigned int u = __float_as_uint(f);
  u += 0x7fffu + ((u >> 16) & 1u);   // RNE
  return (unsigned short)(u >> 16);
}
__device__ __forceinline__ u32 pack2bf(float lo, float hi){
  return (u32)f2bf(lo) | ((u32)f2bf(hi) << 16);
}

// ---------------- cursor init ----------------

__global__ __launch_bounds__(256) void k_initcur(int* __restrict__ range_cursor,
                                                 int* __restrict__ bucket_cursor){
  int t = blockIdx.x * 256 + threadIdx.x;
  if (t < NRANGES) range_cursor[t] = t * RCAP;
  if (t < NBUCKETS) bucket_cursor[t] = t * BCAP;
}

// ---------------- P1: batch-sort edges into 16 dst ranges (full-line flushes) ----------------
// entry = (dst_local_in_range:14 | src:18); range implicit by segment.

__global__ __launch_bounds__(256) void k_p1(const int* __restrict__ src, const int* __restrict__ dst,
                                            int* __restrict__ range_cursor, u32* __restrict__ ebuf1){
  __shared__ u32 stage[BATCH];
  __shared__ int hist[NRANGES], hist2[NRANGES], hbase[NRANGES], gbase[NRANGES];
  const int tid = threadIdx.x;
  const long e0 = (long)blockIdx.x * BATCH;

  if (tid < NRANGES){ hist[tid] = 0; hist2[tid] = 0; }
  __syncthreads();
  for (int i = tid; i < BATCH; i += 256){
    int d = dst[e0 + i];
    atomicAdd(&hist[d / RANGE_N], 1);
  }
  __syncthreads();
  if (tid == 0){ int run = 0; for (int b = 0; b < NRANGES; b++){ hbase[b] = run; run += hist[b]; } }
  __syncthreads();
  if (tid < NRANGES && hist[tid] > 0) gbase[tid] = atomicAdd(&range_cursor[tid], hist[tid]);
  __syncthreads();
  for (int i = tid; i < BATCH; i += 256){
    int d = dst[e0 + i];
    int s = src[e0 + i];
    int r = d / RANGE_N;
    u32 pk = ((u32)(d - r * RANGE_N) << 18) | (u32)s;
    int p = atomicAdd(&hist2[r], 1);
    stage[hbase[r] + p] = pk;
  }
  __syncthreads();
  for (int b = 0; b < NRANGES; b++){
    int len = hist[b];
    int gb = gbase[b], hb = hbase[b];
    for (int i = tid; i < len; i += 256) ebuf1[gb + i] = stage[hb + i];
  }
}

// ---------------- P2: per-range batch-sort into 50 buckets (full-line flushes) ----------------

__global__ __launch_bounds__(256) void k_p2(const u32* __restrict__ ebuf1, const int* __restrict__ range_cursor,
                                            int* __restrict__ bucket_cursor, u32* __restrict__ ebuf2){
  __shared__ u32 stage[BATCH];
  __shared__ int hist[50], hist2[50], hbase[50], gbase[50];
  const int tid = threadIdx.x;
  const int r = blockIdx.x / RBLK;
  const int chunk = blockIdx.x % RBLK;
  const int rlen = range_cursor[r] - r * RCAP;
  const int i0 = chunk * BATCH;
  const int len = min(BATCH, rlen - i0);
  if (len <= 0) return;
  const u32* seg = ebuf1 + (long)r * RCAP + i0;

  if (tid < 50){ hist[tid] = 0; hist2[tid] = 0; }
  __syncthreads();
  for (int i = tid; i < len; i += 256){
    int dl = (int)(seg[i] >> 18);
    atomicAdd(&hist[dl / BUCKET_N], 1);
  }
  __syncthreads();
  if (tid == 0){ int run = 0; for (int b = 0; b < 50; b++){ hbase[b] = run; run += hist[b]; } }
  __syncthreads();
  if (tid < 50 && hist[tid] > 0) gbase[tid] = atomicAdd(&bucket_cursor[r * 50 + tid], hist[tid]);
  __syncthreads();
  for (int i = tid; i < len; i += 256){
    u32 pk = seg[i];
    int b = (int)(pk >> 18) / BUCKET_N;
    int p = atomicAdd(&hist2[b], 1);
    stage[hbase[b] + p] = pk;
  }
  __syncthreads();
  for (int b = 0; b < 50; b++){
    int l = hist[b];
    if (l == 0) continue;
    int gb = gbase[b], hb = hbase[b];
    for (int i = tid; i < l; i += 256) ebuf2[gb + i] = stage[hb + i];
  }
}

// ---------------- scan of 800 bucket lengths -> bucket_base ----------------

__global__ __launch_bounds__(256) void k_scanb(const int* __restrict__ bucket_cursor,
                                               int* __restrict__ bucket_base){
  __shared__ int q[256];
  int tid = threadIdx.x;
  int v[4]; int sum4 = 0;
  if (tid < 200){
    #pragma unroll
    for (int j = 0; j < 4; j++){ int b = 4 * tid + j; v[j] = bucket_cursor[b] - b * BCAP; sum4 += v[j]; }
  }
  q[tid] = sum4; __syncthreads();
  for (int off = 1; off < 256; off <<= 1){
    int t = (tid >= off) ? q[tid - off] : 0;
    __syncthreads();
    q[tid] += t;
    __syncthreads();
  }
  if (tid < 200){
    int run = q[tid] - sum4;
    #pragma unroll
    for (int j = 0; j < 4; j++){ bucket_base[4 * tid + j] = run; run += v[j]; }
  }
}

// ---------------- P3: per-bucket LDS scatter; writes csr AND row_start ----------------

__global__ __launch_bounds__(256) void k_p3(const u32* __restrict__ ebuf2, const int* __restrict__ bucket_cursor,
                                            const int* __restrict__ bucket_base,
                                            int* __restrict__ csr, int* __restrict__ row_start){
  __shared__ int stage[BCAP];
  __shared__ int hist[BUCKET_N], sbase[BUCKET_N], cur[BUCKET_N];
  __shared__ int q[256];
  const int tid = threadIdx.x;
  const int b = blockIdx.x;
  const int n0 = b * BUCKET_N;
  const int dl0 = (b % 50) * BUCKET_N;
  const int len = min(bucket_cursor[b] - b * BCAP, BCAP);
  const int base = bucket_base[b];
  const u32* seg = ebuf2 + (long)b * BCAP;

  if (tid < BUCKET_N){ hist[tid] = 0; cur[tid] = 0; }
  __syncthreads();
  for (int i = tid; i < len; i += 256){
    int local = (int)(seg[i] >> 18) - dl0;
    local = min(max(local, 0), BUCKET_N - 1);   // safety clamp (statistically unreachable)
    atomicAdd(&hist[local], 1);
  }
  __syncthreads();
  {
    int v = (tid < BUCKET_N) ? hist[tid] : 0;
    q[tid] = v; __syncthreads();
    for (int off = 1; off < 256; off <<= 1){
      int t = (tid >= off) ? q[tid - off] : 0;
      __syncthreads();
      q[tid] += t;
      __syncthreads();
    }
    if (tid < BUCKET_N) sbase[tid] = q[tid] - v;
  }
  __syncthreads();
  for (int i = tid; i < len; i += 256){
    u32 pk = seg[i];
    int local = (int)(pk >> 18) - dl0;
    local = min(max(local, 0), BUCKET_N - 1);
    int pos = atomicAdd(&cur[local], 1);
    stage[sbase[local] + pos] = (int)(pk & 0x3FFFFu);
  }
  __syncthreads();
  for (int i = tid; i < len; i += 256) csr[base + i] = stage[i];
  if (tid < BUCKET_N) row_start[n0 + tid] = base + sbase[tid];
  if (b == NBUCKETS - 1 && tid == 0) row_start[N_NODES] = base + len;
}

// ---------------- GEMM [rows,128] @ [128,128] (first layer) -> bf16 xb only ----------------

__global__ __launch_bounds__(256) void k_gemm128(const float* __restrict__ A,
    const float* __restrict__ W, const float* __restrict__ bias,
    u32* __restrict__ xbout)
{
  __shared__ float As[64][132];
  const int tid = threadIdx.x;
  const long row0 = (long)blockIdx.x * 64;

  const float4* A4 = (const float4*)(A + row0 * HID);
  for (int i = tid; i < 64 * 32; i += 256){
    int r = i >> 5, c = i & 31;
    *(float4*)&As[r][c * 4] = A4[r * 32 + c];
  }
  __syncthreads();

  const int cg = tid & 31;
  const int rg = tid >> 5;
  const int c0 = cg * 4;
  float acc[8][4];
  {
    float4 b = *(const float4*)&bias[c0];
    #pragma unroll
    for (int r = 0; r < 8; r++){ acc[r][0]=b.x; acc[r][1]=b.y; acc[r][2]=b.z; acc[r][3]=b.w; }
  }

  for (int k = 0; k < HID; k += 4){
    float4 w0 = *(const float4*)&W[(k + 0) * HID + c0];
    float4 w1 = *(const float4*)&W[(k + 1) * HID + c0];
    float4 w2 = *(const float4*)&W[(k + 2) * HID + c0];
    float4 w3 = *(const float4*)&W[(k + 3) * HID + c0];
    #pragma unroll
    for (int r = 0; r < 8; r++){
      float4 a = *(const float4*)&As[rg * 8 + r][k];
      acc[r][0] = fmaf(a.w, w3.x, fmaf(a.z, w2.x, fmaf(a.y, w1.x, fmaf(a.x, w0.x, acc[r][0]))));
      acc[r][1] = fmaf(a.w, w3.y, fmaf(a.z, w2.y, fmaf(a.y, w1.y, fmaf(a.x, w0.y, acc[r][1]))));
      acc[r][2] = fmaf(a.w, w3.z, fmaf(a.z, w2.z, fmaf(a.y, w1.z, fmaf(a.x, w0.z, acc[r][2]))));
      acc[r][3] = fmaf(a.w, w3.w, fmaf(a.z, w2.w, fmaf(a.y, w1.w, fmaf(a.x, w0.w, acc[r][3]))));
    }
  }

  #pragma unroll
  for (int r = 0; r < 8; r++){
    long row = row0 + rg * 8 + r;
    uint2 p; p.x = pack2bf(acc[r][0], acc[r][1]); p.y = pack2bf(acc[r][2], acc[r][3]);
    *(uint2*)&xbout[(row * HID + c0) >> 1] = p;
  }
}

// ---------------- fused layer: aggregate 32 nodes into LDS, then GEMM+relu+LN ----------------
// bf16-only inter-layer state: working set (xb_old 51MB + xb_new 51MB + csr 26MB)
// fits the 256MB L3 -> gather misses served by L3, not HBM.
// Phase A: 4 waves x 8 nodes each; per-node uint2 gather (16 edges/iter, csr
// prefetch, unmasked bulk + masked tail); self-term read from xb_old (bf16).
// Phase B: acc[4][4]/thread; relu; LN stats via 32-lane shfl_xor butterfly;
// normalize in-register; store bf16 xb only.

__global__ __launch_bounds__(256) void k_fused(const int* __restrict__ row_start,
    const int* __restrict__ csr, const uint2* __restrict__ xb2,
    const float* __restrict__ W, const float* __restrict__ bias,
    const float* __restrict__ gamma, const float* __restrict__ beta,
    u32* __restrict__ xbout)
{
  __shared__ float As[FTILE][132];
  const int tid = threadIdx.x;
  const long row0 = (long)blockIdx.x * FTILE;

  // ---- Phase A: aggregation into As ----
  {
    const int wv = tid >> 6;
    const int lane = tid & 63;
    const int half = lane >> 5, col = lane & 31;
    const uint2* xbc = xb2 + col;

    for (int i = 0; i < FTILE / 4; i++){
      const int r = wv * (FTILE / 4) + i;
      const int node = (int)row0 + r;
      const int s0 = row_start[node], s1 = row_start[node + 1];

      float4 xs = {0.f, 0.f, 0.f, 0.f};
      if (half == 0){
        uint2 sv = xb2[(long)node * 32 + col];
        xs.x = __uint_as_float(sv.x << 16);
        xs.y = __uint_as_float(sv.x & 0xffff0000u);
        xs.z = __uint_as_float(sv.y << 16);
        xs.w = __uint_as_float(sv.y & 0xffff0000u);
      }

      float a0 = 0.f, a1 = 0.f, a2 = 0.f, a3 = 0.f;
      int base = s0;
      int idx[8];
      if (base + 16 <= s1){
        #pragma unroll
        for (int j = 0; j < 8; j++) idx[j] = csr[base + 2*j + half];
      }
      while (base + 16 <= s1){
        uint2 p[8];
        #pragma unroll
        for (int j = 0; j < 8; j++) p[j] = xbc[(long)idx[j] * 32];
        base += 16;
        if (base + 16 <= s1){
          #pragma unroll
          for (int j = 0; j < 8; j++) idx[j] = csr[base + 2*j + half];
        }
        #pragma unroll
        for (int j = 0; j < 8; j++){
          a0 += __uint_as_float(p[j].x << 16);
          a1 += __uint_as_float(p[j].x & 0xffff0000u);
          a2 += __uint_as_float(p[j].y << 16);
          a3 += __uint_as_float(p[j].y & 0xffff0000u);
        }
      }
      if (base < s1){
        const int s1m1 = s1 - 1;
        int ti[8];
        #pragma unroll
        for (int j = 0; j < 8; j++) ti[j] = csr[min(base + 2*j + half, s1m1)];
        uint2 p[8];
        #pragma unroll
        for (int j = 0; j < 8; j++) p[j] = xbc[(long)ti[j] * 32];
        #pragma unroll
        for (int j = 0; j < 8; j++){
          bool act = (base + 2*j + half) < s1;
          float v0 = __uint_as_float(p[j].x << 16);
          float v1 = __uint_as_float(p[j].x & 0xffff0000u);
          float v2 = __uint_as_float(p[j].y << 16);
          float v3 = __uint_as_float(p[j].y & 0xffff0000u);
          a0 += act ? v0 : 0.f;
          a1 += act ? v1 : 0.f;
          a2 += act ? v2 : 0.f;
          a3 += act ? v3 : 0.f;
        }
      }

      a0 += __shfl_down(a0, 32);
      a1 += __shfl_down(a1, 32);
      a2 += __shfl_down(a2, 32);
      a3 += __shfl_down(a3, 32);

      if (half == 0){
        float inv = 1.f / (float)(s1 - s0 + 1);
        float4 rv;
        rv.x = (a0 + xs.x) * inv;
        rv.y = (a1 + xs.y) * inv;
        rv.z = (a2 + xs.z) * inv;
        rv.w = (a3 + xs.w) * inv;
        *(float4*)&As[r][col * 4] = rv;
      }
    }
  }
  __syncthreads();

  // ---- Phase B: GEMM + relu + LN (in-register; half-wave butterfly stats) ----
  const int cg = tid & 31;
  const int rg = tid >> 5;             // 0..7 -> 4 rows each
  const int c0 = cg * 4;
  float acc[4][4];
  {
    float4 b = *(const float4*)&bias[c0];
    #pragma unroll
    for (int r = 0; r < 4; r++){ acc[r][0]=b.x; acc[r][1]=b.y; acc[r][2]=b.z; acc[r][3]=b.w; }
  }

  for (int k = 0; k < HID; k += 4){
    float4 w0 = *(const float4*)&W[(k + 0) * HID + c0];
    float4 w1 = *(const float4*)&W[(k + 1) * HID + c0];
    float4 w2 = *(const float4*)&W[(k + 2) * HID + c0];
    float4 w3 = *(const float4*)&W[(k + 3) * HID + c0];
    #pragma unroll
    for (int r = 0; r < 4; r++){
      float4 a = *(const float4*)&As[rg * 4 + r][k];
      acc[r][0] = fmaf(a.w, w3.x, fmaf(a.z, w2.x, fmaf(a.y, w1.x, fmaf(a.x, w0.x, acc[r][0]))));
      acc[r][1] = fmaf(a.w, w3.y, fmaf(a.z, w2.y, fmaf(a.y, w1.y, fmaf(a.x, w0.y, acc[r][1]))));
      acc[r][2] = fmaf(a.w, w3.z, fmaf(a.z, w2.z, fmaf(a.y, w1.z, fmaf(a.x, w0.z, acc[r][2]))));
      acc[r][3] = fmaf(a.w, w3.w, fmaf(a.z, w2.w, fmaf(a.y, w1.w, fmaf(a.x, w0.w, acc[r][3]))));
    }
  }

  // relu + per-row {sum, sumsq} partials over this thread's 4 cols
  float s[4], s2[4];
  #pragma unroll
  for (int r = 0; r < 4; r++){
    float v0 = fmaxf(acc[r][0], 0.f);
    float v1 = fmaxf(acc[r][1], 0.f);
    float v2 = fmaxf(acc[r][2], 0.f);
    float v3 = fmaxf(acc[r][3], 0.f);
    acc[r][0] = v0; acc[r][1] = v1; acc[r][2] = v2; acc[r][3] = v3;
    s[r]  = (v0 + v1) + (v2 + v3);
    s2[r] = fmaf(v0, v0, fmaf(v1, v1, fmaf(v2, v2, v3 * v3)));
  }
  // butterfly across the 32 lanes holding this row group (xor masks stay in half-wave)
  #pragma unroll
  for (int m = 1; m < 32; m <<= 1){
    #pragma unroll
    for (int r = 0; r < 4; r++){
      s[r]  += __shfl_xor(s[r],  m);
      s2[r] += __shfl_xor(s2[r], m);
    }
  }

  const float4 gm = *(const float4*)&gamma[c0];
  const float4 bt = *(const float4*)&beta[c0];
  #pragma unroll
  for (int r = 0; r < 4; r++){
    float mu = s[r] * (1.f / HID);
    float var = s2[r] * (1.f / HID) - mu * mu;
    float rs = 1.f / sqrtf(var + EPS);
    float4 v;
    v.x = (acc[r][0] - mu) * rs * gm.x + bt.x;
    v.y = (acc[r][1] - mu) * rs * gm.y + bt.y;
    v.z = (acc[r][2] - mu) * rs * gm.z + bt.z;
    v.w = (acc[r][3] - mu) * rs * gm.w + bt.w;
    long row = row0 + rg * 4 + r;
    uint2 p; p.x = pack2bf(v.x, v.y); p.y = pack2bf(v.z, v.w);
    *(uint2*)&xbout[(row * HID + c0) >> 1] = p;
  }
}

// ---------------- output GEMM [rows,128](bf16) @ [128,16] ----------------

__global__ __launch_bounds__(256) void k_gemm_out(const u32* __restrict__ xb,
    const float* __restrict__ Wo, const float* __restrict__ bo, float* __restrict__ out)
{
  __shared__ float As[16][132];
  __shared__ float Wl[HID * OUTF];
  const int tid = threadIdx.x;
  const long row0 = (long)blockIdx.x * 16;
  {
    // 16 rows x 16 uint4 (8 bf16 each) = 256 loads, one per thread
    int r = tid >> 4, u = tid & 15;
    uint4 v = ((const uint4*)xb)[(row0 + r) * 16 + u];
    float* d = &As[r][u * 8];
    d[0] = __uint_as_float(v.x << 16); d[1] = __uint_as_float(v.x & 0xffff0000u);
    d[2] = __uint_as_float(v.y << 16); d[3] = __uint_as_float(v.y & 0xffff0000u);
    d[4] = __uint_as_float(v.z << 16); d[5] = __uint_as_float(v.z & 0xffff0000u);
    d[6] = __uint_as_float(v.w << 16); d[7] = __uint_as_float(v.w & 0xffff0000u);
  }
  for (int i = tid; i < HID * OUTF; i += 256) Wl[i] = Wo[i];
  __syncthreads();
  int col = tid & 15, r = tid >> 4;
  float acc = bo[col];
  for (int k = 0; k < HID; k += 4){
    float4 a = *(const float4*)&As[r][k];
    acc = fmaf(a.x, Wl[(k + 0) * OUTF + col],
          fmaf(a.y, Wl[(k + 1) * OUTF + col],
          fmaf(a.z, Wl[(k + 2) * OUTF + col],
          fmaf(a.w, Wl[(k + 3) * OUTF + col], acc))));
  }
  out[(row0 + r) * OUTF + col] = acc;
}

// ---------------- launch ----------------

extern "C" void kernel_launch(void* const* d_in, const int* in_sizes, int n_in,
                              void* d_out, int out_size, void* d_ws, size_t ws_size,
                              hipStream_t stream)
{
  (void)in_sizes; (void)n_in; (void)out_size; (void)ws_size;
  const float* nodes = (const float*)d_in[0];
  const int*   src   = (const int*)d_in[1];
  const int*   dst   = (const int*)d_in[2];
  const float* W_in  = (const float*)d_in[3];
  const float* b_in  = (const float*)d_in[4];
  const float* Ws    = (const float*)d_in[5];
  const float* bs    = (const float*)d_in[6];
  const float* gam   = (const float*)d_in[7];
  const float* bet   = (const float*)d_in[8];
  const float* W_out = (const float*)d_in[9];
  const float* b_out = (const float*)d_in[10];
  float* out = (float*)d_out;

  size_t off = 0;
  auto bump = [&](size_t bytes) -> char* {
    char* p = (char*)d_ws + off;
    off = (off + bytes + 255) & ~(size_t)255;
    return p;
  };
  int* row_start     = (int*)bump((N_NODES + 1) * sizeof(int));
  int* range_cursor  = (int*)bump(NRANGES * sizeof(int));
  int* bucket_cursor = (int*)bump(NBUCKETS * sizeof(int));
  int* bucket_base   = (int*)bump((NBUCKETS + 1) * sizeof(int));
  int* csr           = (int*)bump((size_t)N_EDGES * sizeof(int));
  u32* xb0           = (u32*)bump((size_t)N_NODES * HID * sizeof(unsigned short));
  u32* xb1           = (u32*)bump((size_t)N_NODES * HID * sizeof(unsigned short));

  // ebuf1 (25.9MB) aliases xb0 (51.2MB): P2 consumes ebuf1 before gemm128 writes xb0.
  // ebuf2 (30.4MB) aliases xb1 (51.2MB): P3 consumes ebuf2 before layer-0 writes xb1.
  u32* ebuf1 = (u32*)xb0;
  u32* ebuf2 = (u32*)xb1;

  k_initcur<<<4, 256, 0, stream>>>(range_cursor, bucket_cursor);
  k_p1<<<NBATCH, 256, 0, stream>>>(src, dst, range_cursor, ebuf1);
  k_p2<<<NRANGES * RBLK, 256, 0, stream>>>(ebuf1, range_cursor, bucket_cursor, ebuf2);
  k_scanb<<<1, 256, 0, stream>>>(bucket_cursor, bucket_base);
  k_p3<<<NBUCKETS, 256, 0, stream>>>(ebuf2, bucket_cursor, bucket_base, csr, row_start);

  k_gemm128<<<N_NODES / 64, 256, 0, stream>>>(nodes, W_in, b_in, xb0);

  const u32* xbi = xb0; u32* xbo = xb1;
  for (int l = 0; l < LAYERS; l++){
    k_fused<<<N_NODES / FTILE, 256, 0, stream>>>(row_start, csr, (const uint2*)xbi,
                                                 Ws + (size_t)l * HID * HID, bs + l * HID,
                                                 gam + l * HID, bet + l * HID, xbo);
    const u32* tb = xbi; xbi = xbo; xbo = (u32*)tb;
  }

  k_gemm_out<<<N_NODES / 16, 256, 0, stream>>>(xbi, W_out, b_out, out);
}